// Round 1
// baseline (81.297 us; speedup 1.0000x reference)
//
#include <hip/hip_runtime.h>

// Symmetrization net: out[j,c] = 8! * sum_i y[i,c], y = relu(x@W1+b1)@W2+b2.
// Every row appears in every position exactly (N-1)! times across all N!
// permutations, so the perms table is never read.

#define NROWS 9
#define DDIM  512
#define HDIM  32
#define OUTC  4
#define FACT8 40320.0f   // 8!

__global__ __launch_bounds__(NROWS * HDIM)
void sym_net_kernel(const float* __restrict__ x,
                    const float* __restrict__ W1,
                    const float* __restrict__ b1,
                    const float* __restrict__ W2,
                    const float* __restrict__ b2,
                    float* __restrict__ out)
{
    __shared__ float hbuf[NROWS][HDIM];
    __shared__ float hsum[HDIM];

    const int t = threadIdx.x;          // 0..287
    const int i = t >> 5;               // row   0..8
    const int h = t & 31;               // hidden 0..31

    // ---- Phase 1: hidden = relu(x @ W1 + b1), one (i,h) pair per thread ----
    float acc0 = 0.f, acc1 = 0.f, acc2 = 0.f, acc3 = 0.f;
    const float4* x4 = (const float4*)(x + i * DDIM);
#pragma unroll 4
    for (int d4 = 0; d4 < DDIM / 4; ++d4) {
        const float4 xv = x4[d4];
        const int d = d4 * 4;
        acc0 += xv.x * W1[(d + 0) * HDIM + h];
        acc1 += xv.y * W1[(d + 1) * HDIM + h];
        acc2 += xv.z * W1[(d + 2) * HDIM + h];
        acc3 += xv.w * W1[(d + 3) * HDIM + h];
    }
    const float hv = (acc0 + acc1) + (acc2 + acc3) + b1[h];
    hbuf[i][h] = hv > 0.f ? hv : 0.f;
    __syncthreads();

    // ---- Phase 2: hsum[h] = sum_i hbuf[i][h] ----
    if (t < HDIM) {
        float s = 0.f;
#pragma unroll
        for (int r = 0; r < NROWS; ++r) s += hbuf[r][t];
        hsum[t] = s;
    }
    __syncthreads();

    // ---- Phase 3: out[j*4+c] = 8! * (sum_h hsum[h]*W2[h][c] + NROWS*b2[c]) ----
    if (t < NROWS * OUTC) {
        const int c = t & 3;
        float s = 0.f;
#pragma unroll
        for (int hh = 0; hh < HDIM; ++hh) s += hsum[hh] * W2[hh * OUTC + c];
        out[t] = FACT8 * (s + (float)NROWS * b2[c]);
    }
}

extern "C" void kernel_launch(void* const* d_in, const int* in_sizes, int n_in,
                              void* d_out, int out_size, void* d_ws, size_t ws_size,
                              hipStream_t stream)
{
    const float* x  = (const float*)d_in[0];   // [9, 512]
    const float* W1 = (const float*)d_in[1];   // [512, 32]
    const float* b1 = (const float*)d_in[2];   // [32]
    const float* W2 = (const float*)d_in[3];   // [32, 4]
    const float* b2 = (const float*)d_in[4];   // [4]
    // d_in[5] = perms [362880, 9] — mathematically unused (closed form).
    float* out = (float*)d_out;                // [9, 4] = 36 floats

    sym_net_kernel<<<1, NROWS * HDIM, 0, stream>>>(x, W1, b1, W2, b2, out);
}

// Round 2
// 70.640 us; speedup vs baseline: 1.1509x; 1.1509x over previous
//
#include <hip/hip_runtime.h>

// Symmetrization net, closed form: out[j,c] = 8! * (sum_h hsum[h]*W2[h,c] + 9*b2[c])
// where hsum[h] = sum_i relu((x@W1)[i,h] + b1[h]). Perms table never read.
//
// R1 analysis: single-block version was latency-chain-bound (~40 µs): 128
// serially-dependent cold-load iterations on one CU. Split D across 64 blocks
// so each thread's loads form ONE independent batch (single latency exposure),
// then a tiny reduce kernel finishes. No atomics, no memset: partials in d_ws.

#define NROWS 9
#define DDIM  512
#define HDIM  32
#define OUTC  4
#define NBLK  64
#define DPB   (DDIM / NBLK)      // 8 d-values per block
#define NPAIR (NROWS * HDIM)     // 288 (i,h) pairs
#define FACT8 40320.0f           // 8!

// ---- Kernel A: partial pre-activations over a d-slice -----------------------
// Block b owns d in [b*8, b*8+8). Thread t=(i,h). part[b][t] = sum_k x[i][d0+k]*W1[d0+k][h].
// Per thread: 2 float4 x-loads (broadcast within h-group) + 8 coalesced W1 loads,
// all independent -> one vmcnt batch, 8 fmas, one store.
__global__ __launch_bounds__(NPAIR)
void sym_partial_kernel(const float* __restrict__ x,
                        const float* __restrict__ W1,
                        float* __restrict__ part)
{
    const int t  = threadIdx.x;        // 0..287
    const int i  = t >> 5;             // row    0..8
    const int h  = t & 31;             // hidden 0..31
    const int d0 = blockIdx.x * DPB;

    const float4* x4 = (const float4*)(x + i * DDIM + d0);  // d0 % 8 == 0 -> 16B aligned
    const float4 xa = x4[0];
    const float4 xb = x4[1];

    float w[DPB];
#pragma unroll
    for (int k = 0; k < DPB; ++k) w[k] = W1[(d0 + k) * HDIM + h];

    float s = (xa.x * w[0] + xa.y * w[1]) + (xa.z * w[2] + xa.w * w[3])
            + (xb.x * w[4] + xb.y * w[5]) + (xb.z * w[6] + xb.w * w[7]);

    part[blockIdx.x * NPAIR + t] = s;
}

// ---- Kernel B: reduce partials, bias+relu, row-sum, W2 matvec ---------------
__global__ __launch_bounds__(NPAIR)
void sym_finish_kernel(const float* __restrict__ part,
                       const float* __restrict__ b1,
                       const float* __restrict__ W2,
                       const float* __restrict__ b2,
                       float* __restrict__ out)
{
    __shared__ float hbuf[NROWS][HDIM];
    __shared__ float hsum[HDIM];

    const int t = threadIdx.x;         // 0..287
    const int i = t >> 5;
    const int h = t & 31;

    // Sum 64 partials (73 KB total, L2-hot from kernel A). Coalesced across t;
    // 4 independent accumulators, unrolled -> batched loads.
    float s0 = 0.f, s1 = 0.f, s2 = 0.f, s3 = 0.f;
#pragma unroll
    for (int b = 0; b < NBLK; b += 4) {
        s0 += part[(b + 0) * NPAIR + t];
        s1 += part[(b + 1) * NPAIR + t];
        s2 += part[(b + 2) * NPAIR + t];
        s3 += part[(b + 3) * NPAIR + t];
    }
    const float hv = (s0 + s1) + (s2 + s3) + b1[h];
    hbuf[i][h] = hv > 0.f ? hv : 0.f;
    __syncthreads();

    if (t < HDIM) {
        float s = 0.f;
#pragma unroll
        for (int r = 0; r < NROWS; ++r) s += hbuf[r][t];
        hsum[t] = s;
    }
    __syncthreads();

    if (t < NROWS * OUTC) {
        const int c = t & 3;
        float s = 0.f;
#pragma unroll
        for (int hh = 0; hh < HDIM; ++hh) s += hsum[hh] * W2[hh * OUTC + c];
        out[t] = FACT8 * (s + (float)NROWS * b2[c]);
    }
}

extern "C" void kernel_launch(void* const* d_in, const int* in_sizes, int n_in,
                              void* d_out, int out_size, void* d_ws, size_t ws_size,
                              hipStream_t stream)
{
    const float* x  = (const float*)d_in[0];   // [9, 512]
    const float* W1 = (const float*)d_in[1];   // [512, 32]
    const float* b1 = (const float*)d_in[2];   // [32]
    const float* W2 = (const float*)d_in[3];   // [32, 4]
    const float* b2 = (const float*)d_in[4];   // [4]
    // d_in[5] = perms [362880, 9] — mathematically unused (closed form).
    float* out  = (float*)d_out;               // [9, 4]
    float* part = (float*)d_ws;                // [64][288] floats = 73728 B

    sym_partial_kernel<<<NBLK, NPAIR, 0, stream>>>(x, W1, part);
    sym_finish_kernel<<<1, NPAIR, 0, stream>>>(part, b1, W2, b2, out);
}